// Round 5
// baseline (754.917 us; speedup 1.0000x reference)
//
#include <hip/hip_runtime.h>

#define NE 2048
#define VOC 32000

typedef __attribute__((ext_vector_type(8))) short short8;
typedef __attribute__((ext_vector_type(4))) float f32x4;

// ws layout (bytes):
#define OFF_LMWT   0u          // [32000][64] bf16   4,096,000
#define OFF_WNBRT  4096000u    // [128][512] bf16      131,072
#define OFF_WSELFT 4227072u    // [128][512] bf16      131,072
#define OFF_AALL   4358144u    // [6144][512] bf16   6,291,456
#define OFF_MSG    10649600u   // [2048][128] f32    1,048,576
#define OFF_XS     11698176u   // [2048][128] f32    1,048,576
#define OFF_XD     12746752u   // [2048][128] f32    1,048,576
#define OFF_XB     13795328u   // [4096][64] bf16      524,288
#define OFF_RSUMS  14319616u   // [4096] f32            16,384

__device__ __forceinline__ short f2bf(float f) {
  union { float f; unsigned u; } c; c.f = f;
  unsigned r = (c.u + 0x7FFFu + ((c.u >> 16) & 1u)) >> 16;
  return (short)r;
}

__device__ __forceinline__ float wave_sum64(float v) {
#pragma unroll
  for (int m = 1; m < 64; m <<= 1) v += __shfl_xor(v, m, 64);
  return v;
}

// ---------------- K0: weight transpose-convert + rsums zero + labels --------
__global__ __launch_bounds__(256) void k0_prep(
    const float* __restrict__ lm_W, const float* __restrict__ W_nbr,
    const float* __restrict__ W_self, const int* __restrict__ edge_tokens,
    short* __restrict__ lm_Wt, short* __restrict__ Wnbrt,
    short* __restrict__ Wselft, float* __restrict__ rsums,
    float* __restrict__ out_labels) {
  int b = blockIdx.x, t = threadIdx.x;
  if (b == 532) {  // zero row sums
    for (int i = t; i < 4096; i += 256) rsums[i] = 0.f;
    return;
  }
  if (b >= 533) {  // labels: 16 blocks x 1024 elems
    int base = (b - 533) * 1024 + t;
#pragma unroll
    for (int it = 0; it < 4; ++it) {
      int i = base + it * 256;
      int e = i >> 3;
      int tok = edge_tokens[i];
      float val = -100.f;
      if (e == 0 && tok >= 4) val = (float)tok;  // row 0, non-special kept
      out_labels[i] = val;
    }
    return;
  }
  // transpose-convert fp32 [R][C] -> bf16 [C][R]
  const float* src; short* dst; int R, C, tb;
  if (b < 500)      { src = lm_W;   dst = lm_Wt;  R = 64;  C = VOC; tb = b; }
  else if (b < 516) { src = W_nbr;  dst = Wnbrt;  R = 512; C = 128; tb = b - 500; }
  else              { src = W_self; dst = Wselft; R = 512; C = 128; tb = b - 516; }
  __shared__ float tile[64][65];
  int tiles_c = C >> 6;
  int r0 = (tb / tiles_c) << 6;
  int c0 = (tb % tiles_c) << 6;
  int lr = t >> 6, lc = t & 63;
#pragma unroll
  for (int rr = 0; rr < 16; ++rr) {
    int r = rr * 4 + lr;
    tile[r][lc] = src[(r0 + r) * C + c0 + lc];
  }
  __syncthreads();
#pragma unroll
  for (int rr = 0; rr < 16; ++rr) {
    int cc = rr * 4 + lr;
    dst[(c0 + cc) * R + r0 + lc] = f2bf(tile[lc][cc]);
  }
}

// ---------------- K1a: gather embeddings into A_all [6144][512] bf16 --------
__global__ __launch_bounds__(256) void k1a_gather(
    const int* __restrict__ node_tokens, const int* __restrict__ edge_tokens,
    const int* __restrict__ edge_index, const float* __restrict__ embed,
    short* __restrict__ A_all) {
  int t = blockIdx.x * 256 + threadIdx.x;  // < 393216
  int row = t >> 6;
  int rem = t & 63;
  int j = rem >> 3;
  int h0 = (rem & 7) << 3;
  int kind = row >> 11;
  int e = row & 2047;
  int n = (kind == 2) ? edge_index[NE + e] : edge_index[e];
  int tok = node_tokens[n * 8 + j];
  const float* ep = embed + tok * 64 + h0;
  f32x4 a0 = *(const f32x4*)ep;
  f32x4 a1 = *(const f32x4*)(ep + 4);
  if (kind == 0) {
    int etok = edge_tokens[e * 8 + j];
    const float* ep2 = embed + etok * 64 + h0;
    a0 += *(const f32x4*)ep2;
    a1 += *(const f32x4*)(ep2 + 4);
  }
  short8 ov;
#pragma unroll
  for (int i = 0; i < 4; ++i) { ov[i] = f2bf(a0[i]); ov[4 + i] = f2bf(a1[i]); }
  *(short8*)(A_all + row * 512 + j * 64 + h0) = ov;
}

// ---------------- K1b: GEMM [6144,512]@[512,128] bf16 MFMA -> msg/xs/xd -----
__global__ __launch_bounds__(256) void k1b_gemm(
    const short* __restrict__ A_all, const short* __restrict__ Wnbrt,
    const short* __restrict__ Wselft, float* __restrict__ msg,
    float* __restrict__ xsarr, float* __restrict__ xdarr) {
  int t = threadIdx.x;
  int w = t >> 6, l = t & 63;
  int lm = l & 15, lq = l >> 4;
  int r0 = blockIdx.x * 32;
  int kind = r0 >> 11;
  const short* B = (kind == 0) ? Wnbrt : Wselft;
  float* outp = (kind == 0) ? msg : (kind == 1) ? xsarr : xdarr;
  int orow0 = r0 & 2047;
  f32x4 acc[2][2] = {};
  for (int ks = 0; ks < 16; ++ks) {
    int kk = ks * 32 + lq * 8;
    short8 a0 = *(const short8*)(A_all + (r0 + lm) * 512 + kk);
    short8 a1 = *(const short8*)(A_all + (r0 + 16 + lm) * 512 + kk);
    short8 b0 = *(const short8*)(B + (w * 32 + lm) * 512 + kk);
    short8 b1 = *(const short8*)(B + (w * 32 + 16 + lm) * 512 + kk);
    acc[0][0] = __builtin_amdgcn_mfma_f32_16x16x32_bf16(a0, b0, acc[0][0], 0, 0, 0);
    acc[0][1] = __builtin_amdgcn_mfma_f32_16x16x32_bf16(a0, b1, acc[0][1], 0, 0, 0);
    acc[1][0] = __builtin_amdgcn_mfma_f32_16x16x32_bf16(a1, b0, acc[1][0], 0, 0, 0);
    acc[1][1] = __builtin_amdgcn_mfma_f32_16x16x32_bf16(a1, b1, acc[1][1], 0, 0, 0);
  }
#pragma unroll
  for (int mf = 0; mf < 2; ++mf)
#pragma unroll
    for (int nf = 0; nf < 2; ++nf)
#pragma unroll
      for (int r = 0; r < 4; ++r) {
        int m = orow0 + mf * 16 + lq * 4 + r;
        int n = w * 32 + nf * 16 + lm;
        outp[m * 128 + n] = acc[mf][nf][r];
      }
}

// ---------------- K23: per-edge agg scan + relu + transformer ---------------
__global__ __launch_bounds__(128) void k23_fused(
    const int* __restrict__ edge_index, const float* __restrict__ msg,
    const float* __restrict__ xsarr, const float* __restrict__ xdarr,
    const float* __restrict__ Wq, const float* __restrict__ Wk,
    const float* __restrict__ Wv, const float* __restrict__ Wo,
    const float* __restrict__ W1, const float* __restrict__ W2,
    short* __restrict__ Xb) {
  int e = blockIdx.x, t = threadIdx.x;
  int s = t >> 6, h = t & 63;
  __shared__ __align__(16) float xlds[2][64];
  __shared__ float klds[2][64];
  __shared__ float vlds[2][64];
  __shared__ __align__(16) float alds[2][64];
  __shared__ __align__(16) float h1[2][256];
  __shared__ int lst[2][128];
  __shared__ int lcnt[2];

  int srcu = edge_index[e], dstu = edge_index[NE + e];
  float acc_s = 0.f, acc_d = 0.f;
  for (int c = 0; c < 16; ++c) {  // scan all 2048 dst entries in chunks of 128
    if (t < 2) lcnt[t] = 0;
    __syncthreads();
    int ep = c * 128 + t;
    int d = edge_index[NE + ep];
    if (d == srcu) { int p = atomicAdd(&lcnt[0], 1); lst[0][p] = ep; }
    if (d == dstu) { int p = atomicAdd(&lcnt[1], 1); lst[1][p] = ep; }
    __syncthreads();
    int c0 = lcnt[0], c1 = lcnt[1];
    for (int i = 0; i < c0; ++i) acc_s += msg[lst[0][i] * 128 + t];
    for (int i = 0; i < c1; ++i) acc_d += msg[lst[1][i] * 128 + t];
    __syncthreads();
  }
  float hs = fmaxf(xsarr[e * 128 + t] + acc_s, 0.f);
  float hd = fmaxf(xdarr[e * 128 + t] + acc_d, 0.f);
  float xv = hs + hd;  // edge_h element t -> x[s][h]
  ((float*)xlds)[t] = xv;
  __syncthreads();

  // QKV
  float q = 0.f, kk = 0.f, vv = 0.f;
  for (int k4 = 0; k4 < 64; k4 += 4) {
    f32x4 xr = *(const f32x4*)&xlds[s][k4];
#pragma unroll
    for (int i = 0; i < 4; ++i) {
      int kidx = k4 + i;
      q  += xr[i] * Wq[kidx * 64 + h];
      kk += xr[i] * Wk[kidx * 64 + h];
      vv += xr[i] * Wv[kidx * 64 + h];
    }
  }
  klds[s][h] = kk;
  vlds[s][h] = vv;
  __syncthreads();
  // attention (S=2), wave s = row s
  float sc0 = wave_sum64(q * klds[0][h]) * 0.125f;
  float sc1 = wave_sum64(q * klds[1][h]) * 0.125f;
  float mx = fmaxf(sc0, sc1);
  float e0 = __expf(sc0 - mx), e1 = __expf(sc1 - mx);
  float pin = 1.f / (e0 + e1);
  float av = (e0 * pin) * vlds[0][h] + (e1 * pin) * vlds[1][h];
  alds[s][h] = av;
  __syncthreads();
  // output projection
  float o = 0.f;
  for (int k4 = 0; k4 < 64; k4 += 4) {
    f32x4 ar = *(const f32x4*)&alds[s][k4];
#pragma unroll
    for (int i = 0; i < 4; ++i) o += ar[i] * Wo[(k4 + i) * 64 + h];
  }
  float xa = xv + o;
  float mean = wave_sum64(xa) * (1.f / 64.f);
  float var = wave_sum64(xa * xa) * (1.f / 64.f) - mean * mean;
  float x1 = (xa - mean) * rsqrtf(var + 1e-5f);
  __syncthreads();
  ((float*)xlds)[t] = x1;
  __syncthreads();
  // FFN1: thread computes f = h*4..h*4+3
  f32x4 hh = {0.f, 0.f, 0.f, 0.f};
  int f0 = h * 4;
  for (int k4 = 0; k4 < 64; k4 += 4) {
    f32x4 xr = *(const f32x4*)&xlds[s][k4];
#pragma unroll
    for (int i = 0; i < 4; ++i) {
      f32x4 wrow = *(const f32x4*)&W1[(k4 + i) * 256 + f0];
#pragma unroll
      for (int jj = 0; jj < 4; ++jj) hh[jj] += xr[i] * wrow[jj];
    }
  }
#pragma unroll
  for (int jj = 0; jj < 4; ++jj) hh[jj] = fmaxf(hh[jj], 0.f);
  *(f32x4*)&h1[s][f0] = hh;
  __syncthreads();
  // FFN2
  float o2 = 0.f;
  for (int f4 = 0; f4 < 256; f4 += 4) {
    f32x4 hr = *(const f32x4*)&h1[s][f4];
#pragma unroll
    for (int i = 0; i < 4; ++i) o2 += hr[i] * W2[(f4 + i) * 64 + h];
  }
  float xb2 = x1 + o2;
  float mean2 = wave_sum64(xb2) * (1.f / 64.f);
  float var2 = wave_sum64(xb2 * xb2) * (1.f / 64.f) - mean2 * mean2;
  float x2 = (xb2 - mean2) * rsqrtf(var2 + 1e-5f);
  Xb[(e * 2 + s) * 64 + h] = f2bf(x2);
}

// ---------------- D1: sum of exp(logits) per row (MFMA) ---------------------
// Tile-resident: grid = 125 vocab tiles x 16 rowsplits. lm_Wt fragments for
// the block's tile are loaded ONCE into registers (32 VGPR) and reused across
// 4 rowgroups -> lm_Wt logical reads drop 64x (no L2-retention assumption).
__global__ __launch_bounds__(256) void d1_sums(
    const short* __restrict__ Xb, const short* __restrict__ lm_Wt,
    const float* __restrict__ lm_b, float* __restrict__ rsums) {
  int t = threadIdx.x;
  int w = t >> 6, l = t & 63;
  int lm = l & 15, lq = l >> 4;
  int tile = blockIdx.x >> 4;   // 0..124 (125*256 = 32000 exact)
  int rs = blockIdx.x & 15;     // 0..15
  int n0 = tile * 256 + w * 64;
  short8 bf[4][2];
#pragma unroll
  for (int nf = 0; nf < 4; ++nf)
#pragma unroll
    for (int ks = 0; ks < 2; ++ks)
      bf[nf][ks] = *(const short8*)(lm_Wt + (n0 + nf * 16 + lm) * 64 + ks * 32 + lq * 8);
  float bv[4];
#pragma unroll
  for (int nf = 0; nf < 4; ++nf) bv[nf] = lm_b[n0 + nf * 16 + lm];
  __shared__ float ls[4][64];
  for (int rg = 0; rg < 4; ++rg) {
    int mb0 = rs * 256 + rg * 64;
    short8 af[4][2];
#pragma unroll
    for (int mf = 0; mf < 4; ++mf)
#pragma unroll
      for (int ks = 0; ks < 2; ++ks)
        af[mf][ks] = *(const short8*)(Xb + (mb0 + mf * 16 + lm) * 64 + ks * 32 + lq * 8);
    f32x4 acc[4][4] = {};
#pragma unroll
    for (int ks = 0; ks < 2; ++ks)
#pragma unroll
      for (int mf = 0; mf < 4; ++mf)
#pragma unroll
        for (int nf = 0; nf < 4; ++nf)
          acc[mf][nf] = __builtin_amdgcn_mfma_f32_16x16x32_bf16(af[mf][ks], bf[nf][ks], acc[mf][nf], 0, 0, 0);
#pragma unroll
    for (int mf = 0; mf < 4; ++mf)
#pragma unroll
      for (int r = 0; r < 4; ++r) {
        float s = 0.f;
#pragma unroll
        for (int nf = 0; nf < 4; ++nf) s += __expf(acc[mf][nf][r] + bv[nf]);
        // reduce over the 16 lm lanes (vocab cols within the wave)
        s += __shfl_xor(s, 1, 64);
        s += __shfl_xor(s, 2, 64);
        s += __shfl_xor(s, 4, 64);
        s += __shfl_xor(s, 8, 64);
        if (lm == 0) ls[w][mf * 16 + lq * 4 + r] = s;
      }
    __syncthreads();
    if (t < 64) atomicAdd(&rsums[mb0 + t], ls[0][t] + ls[1][t] + ls[2][t] + ls[3][t]);
    __syncthreads();  // protect ls before next rowgroup overwrites it
  }
}

// ---------------- D2: recompute logits, write probs -------------------------
// Tile-resident like d1; swapped operands (A = lm_Wt -> lane holds 4
// consecutive vocab entries) for dwordx4 non-temporal stores. No LDS, no
// barriers: per-lane 1/rsums load (rsums is 16 KB, L2-hot).
__global__ __launch_bounds__(256) void d2_probs(
    const short* __restrict__ Xb, const short* __restrict__ lm_Wt,
    const float* __restrict__ lm_b, const float* __restrict__ rsums,
    float* __restrict__ out_probs) {
  int t = threadIdx.x;
  int w = t >> 6, l = t & 63;
  int lm = l & 15, lq = l >> 4;
  int tile = blockIdx.x >> 4;   // 0..124
  int rs = blockIdx.x & 15;     // 0..15
  int n0 = tile * 256 + w * 64;
  short8 wf[4][2];
#pragma unroll
  for (int nf = 0; nf < 4; ++nf)
#pragma unroll
    for (int ks = 0; ks < 2; ++ks)
      wf[nf][ks] = *(const short8*)(lm_Wt + (n0 + nf * 16 + lm) * 64 + ks * 32 + lq * 8);
  f32x4 bq[4];
#pragma unroll
  for (int nf = 0; nf < 4; ++nf)
    bq[nf] = *(const f32x4*)(lm_b + n0 + nf * 16 + lq * 4);
  for (int rg = 0; rg < 4; ++rg) {
    int mb0 = rs * 256 + rg * 64;
    short8 xf[4][2];
#pragma unroll
    for (int mf = 0; mf < 4; ++mf)
#pragma unroll
      for (int ks = 0; ks < 2; ++ks)
        xf[mf][ks] = *(const short8*)(Xb + (mb0 + mf * 16 + lm) * 64 + ks * 32 + lq * 8);
    float iv[4];
#pragma unroll
    for (int mf = 0; mf < 4; ++mf) iv[mf] = 1.f / rsums[mb0 + mf * 16 + lm];
    f32x4 acc[4][4] = {};
#pragma unroll
    for (int ks = 0; ks < 2; ++ks)
#pragma unroll
      for (int mf = 0; mf < 4; ++mf)
#pragma unroll
        for (int nf = 0; nf < 4; ++nf)
          acc[mf][nf] = __builtin_amdgcn_mfma_f32_16x16x32_bf16(wf[nf][ks], xf[mf][ks], acc[mf][nf], 0, 0, 0);
#pragma unroll
    for (int mf = 0; mf < 4; ++mf) {
      size_t rowbase = (size_t)(mb0 + mf * 16 + lm) * VOC;
#pragma unroll
      for (int nf = 0; nf < 4; ++nf) {
        f32x4 p;
#pragma unroll
        for (int r = 0; r < 4; ++r)
          p[r] = __expf(acc[mf][nf][r] + bq[nf][r]) * iv[mf];
        __builtin_nontemporal_store(p, (f32x4*)(out_probs + rowbase + n0 + nf * 16 + lq * 4));
      }
    }
  }
}

extern "C" void kernel_launch(void* const* d_in, const int* in_sizes, int n_in,
                              void* d_out, int out_size, void* d_ws, size_t ws_size,
                              hipStream_t stream) {
  const int* node_tokens = (const int*)d_in[0];
  const int* edge_tokens = (const int*)d_in[1];
  const int* edge_index  = (const int*)d_in[2];
  const float* embed     = (const float*)d_in[3];
  const float* W_self    = (const float*)d_in[4];
  const float* W_nbr     = (const float*)d_in[5];
  const float* Wq        = (const float*)d_in[6];
  const float* Wk        = (const float*)d_in[7];
  const float* Wv        = (const float*)d_in[8];
  const float* Wo        = (const float*)d_in[9];
  const float* W1        = (const float*)d_in[10];
  const float* W2        = (const float*)d_in[11];
  const float* lm_W      = (const float*)d_in[12];
  const float* lm_b      = (const float*)d_in[13];

  char* ws = (char*)d_ws;
  short* lm_Wt  = (short*)(ws + OFF_LMWT);
  short* Wnbrt  = (short*)(ws + OFF_WNBRT);
  short* Wselft = (short*)(ws + OFF_WSELFT);
  short* A_all  = (short*)(ws + OFF_AALL);
  float* msg    = (float*)(ws + OFF_MSG);
  float* xsarr  = (float*)(ws + OFF_XS);
  float* xdarr  = (float*)(ws + OFF_XD);
  short* Xb     = (short*)(ws + OFF_XB);
  float* rsums  = (float*)(ws + OFF_RSUMS);
  float* out    = (float*)d_out;  // [16384 labels][131072000 probs]

  k0_prep<<<549, 256, 0, stream>>>(lm_W, W_nbr, W_self, edge_tokens,
                                   lm_Wt, Wnbrt, Wselft, rsums, out);
  k1a_gather<<<1536, 256, 0, stream>>>(node_tokens, edge_tokens, edge_index,
                                       embed, A_all);
  k1b_gemm<<<192, 256, 0, stream>>>(A_all, Wnbrt, Wselft, msg, xsarr, xdarr);
  k23_fused<<<2048, 128, 0, stream>>>(edge_index, msg, xsarr, xdarr,
                                      Wq, Wk, Wv, Wo, W1, W2, Xb);
  d1_sums<<<2000, 256, 0, stream>>>(Xb, lm_Wt, lm_b, rsums);
  d2_probs<<<2000, 256, 0, stream>>>(Xb, lm_Wt, lm_b, rsums, out + 16384);
}

// Round 6
// 689.362 us; speedup vs baseline: 1.0951x; 1.0951x over previous
//
#include <hip/hip_runtime.h>

#define NE 2048
#define VOC 32000

typedef __attribute__((ext_vector_type(8))) short short8;
typedef __attribute__((ext_vector_type(4))) float f32x4;

// ws layout (bytes):
#define OFF_LMWT   0u          // [32000][64] bf16   4,096,000
#define OFF_WNBRT  4096000u    // [128][512] bf16      131,072
#define OFF_WSELFT 4227072u    // [128][512] bf16      131,072
#define OFF_AALL   4358144u    // [6144][512] bf16   6,291,456
#define OFF_MSG    10649600u   // [2048][128] f32    1,048,576
#define OFF_XS     11698176u   // [2048][128] f32    1,048,576
#define OFF_XD     12746752u   // [2048][128] f32    1,048,576
#define OFF_XB     13795328u   // [4096][64] bf16      524,288
#define OFF_RSUMS  14319616u   // [4096] f32            16,384

__device__ __forceinline__ short f2bf(float f) {
  union { float f; unsigned u; } c; c.f = f;
  unsigned r = (c.u + 0x7FFFu + ((c.u >> 16) & 1u)) >> 16;
  return (short)r;
}

__device__ __forceinline__ float wave_sum64(float v) {
#pragma unroll
  for (int m = 1; m < 64; m <<= 1) v += __shfl_xor(v, m, 64);
  return v;
}

// ---------------- K0: weight transpose-convert + rsums zero + labels --------
__global__ __launch_bounds__(256) void k0_prep(
    const float* __restrict__ lm_W, const float* __restrict__ W_nbr,
    const float* __restrict__ W_self, const int* __restrict__ edge_tokens,
    short* __restrict__ lm_Wt, short* __restrict__ Wnbrt,
    short* __restrict__ Wselft, float* __restrict__ rsums,
    float* __restrict__ out_labels) {
  int b = blockIdx.x, t = threadIdx.x;
  if (b == 532) {  // zero row sums
    for (int i = t; i < 4096; i += 256) rsums[i] = 0.f;
    return;
  }
  if (b >= 533) {  // labels: 16 blocks x 1024 elems
    int base = (b - 533) * 1024 + t;
#pragma unroll
    for (int it = 0; it < 4; ++it) {
      int i = base + it * 256;
      int e = i >> 3;
      int tok = edge_tokens[i];
      float val = -100.f;
      if (e == 0 && tok >= 4) val = (float)tok;  // row 0, non-special kept
      out_labels[i] = val;
    }
    return;
  }
  // transpose-convert fp32 [R][C] -> bf16 [C][R]
  const float* src; short* dst; int R, C, tb;
  if (b < 500)      { src = lm_W;   dst = lm_Wt;  R = 64;  C = VOC; tb = b; }
  else if (b < 516) { src = W_nbr;  dst = Wnbrt;  R = 512; C = 128; tb = b - 500; }
  else              { src = W_self; dst = Wselft; R = 512; C = 128; tb = b - 516; }
  __shared__ float tile[64][65];
  int tiles_c = C >> 6;
  int r0 = (tb / tiles_c) << 6;
  int c0 = (tb % tiles_c) << 6;
  int lr = t >> 6, lc = t & 63;
#pragma unroll
  for (int rr = 0; rr < 16; ++rr) {
    int r = rr * 4 + lr;
    tile[r][lc] = src[(r0 + r) * C + c0 + lc];
  }
  __syncthreads();
#pragma unroll
  for (int rr = 0; rr < 16; ++rr) {
    int cc = rr * 4 + lr;
    dst[(c0 + cc) * R + r0 + lc] = f2bf(tile[lc][cc]);
  }
}

// ---------------- K1a: gather embeddings into A_all [6144][512] bf16 --------
__global__ __launch_bounds__(256) void k1a_gather(
    const int* __restrict__ node_tokens, const int* __restrict__ edge_tokens,
    const int* __restrict__ edge_index, const float* __restrict__ embed,
    short* __restrict__ A_all) {
  int t = blockIdx.x * 256 + threadIdx.x;  // < 393216
  int row = t >> 6;
  int rem = t & 63;
  int j = rem >> 3;
  int h0 = (rem & 7) << 3;
  int kind = row >> 11;
  int e = row & 2047;
  int n = (kind == 2) ? edge_index[NE + e] : edge_index[e];
  int tok = node_tokens[n * 8 + j];
  const float* ep = embed + tok * 64 + h0;
  f32x4 a0 = *(const f32x4*)ep;
  f32x4 a1 = *(const f32x4*)(ep + 4);
  if (kind == 0) {
    int etok = edge_tokens[e * 8 + j];
    const float* ep2 = embed + etok * 64 + h0;
    a0 += *(const f32x4*)ep2;
    a1 += *(const f32x4*)(ep2 + 4);
  }
  short8 ov;
#pragma unroll
  for (int i = 0; i < 4; ++i) { ov[i] = f2bf(a0[i]); ov[4 + i] = f2bf(a1[i]); }
  *(short8*)(A_all + row * 512 + j * 64 + h0) = ov;
}

// ---------------- K1b: GEMM [6144,512]@[512,128] bf16 MFMA -> msg/xs/xd -----
__global__ __launch_bounds__(256) void k1b_gemm(
    const short* __restrict__ A_all, const short* __restrict__ Wnbrt,
    const short* __restrict__ Wselft, float* __restrict__ msg,
    float* __restrict__ xsarr, float* __restrict__ xdarr) {
  int t = threadIdx.x;
  int w = t >> 6, l = t & 63;
  int lm = l & 15, lq = l >> 4;
  int r0 = blockIdx.x * 32;
  int kind = r0 >> 11;
  const short* B = (kind == 0) ? Wnbrt : Wselft;
  float* outp = (kind == 0) ? msg : (kind == 1) ? xsarr : xdarr;
  int orow0 = r0 & 2047;
  f32x4 acc[2][2] = {};
  for (int ks = 0; ks < 16; ++ks) {
    int kk = ks * 32 + lq * 8;
    short8 a0 = *(const short8*)(A_all + (r0 + lm) * 512 + kk);
    short8 a1 = *(const short8*)(A_all + (r0 + 16 + lm) * 512 + kk);
    short8 b0 = *(const short8*)(B + (w * 32 + lm) * 512 + kk);
    short8 b1 = *(const short8*)(B + (w * 32 + 16 + lm) * 512 + kk);
    acc[0][0] = __builtin_amdgcn_mfma_f32_16x16x32_bf16(a0, b0, acc[0][0], 0, 0, 0);
    acc[0][1] = __builtin_amdgcn_mfma_f32_16x16x32_bf16(a0, b1, acc[0][1], 0, 0, 0);
    acc[1][0] = __builtin_amdgcn_mfma_f32_16x16x32_bf16(a1, b0, acc[1][0], 0, 0, 0);
    acc[1][1] = __builtin_amdgcn_mfma_f32_16x16x32_bf16(a1, b1, acc[1][1], 0, 0, 0);
  }
#pragma unroll
  for (int mf = 0; mf < 2; ++mf)
#pragma unroll
    for (int nf = 0; nf < 2; ++nf)
#pragma unroll
      for (int r = 0; r < 4; ++r) {
        int m = orow0 + mf * 16 + lq * 4 + r;
        int n = w * 32 + nf * 16 + lm;
        outp[m * 128 + n] = acc[mf][nf][r];
      }
}

// ---------------- K23: per-edge agg scan + relu + transformer ---------------
__global__ __launch_bounds__(128) void k23_fused(
    const int* __restrict__ edge_index, const float* __restrict__ msg,
    const float* __restrict__ xsarr, const float* __restrict__ xdarr,
    const float* __restrict__ Wq, const float* __restrict__ Wk,
    const float* __restrict__ Wv, const float* __restrict__ Wo,
    const float* __restrict__ W1, const float* __restrict__ W2,
    short* __restrict__ Xb) {
  int e = blockIdx.x, t = threadIdx.x;
  int s = t >> 6, h = t & 63;
  __shared__ __align__(16) float xlds[2][64];
  __shared__ float klds[2][64];
  __shared__ float vlds[2][64];
  __shared__ __align__(16) float alds[2][64];
  __shared__ __align__(16) float h1[2][256];
  __shared__ int lst[2][128];
  __shared__ int lcnt[2];

  int srcu = edge_index[e], dstu = edge_index[NE + e];
  float acc_s = 0.f, acc_d = 0.f;
  for (int c = 0; c < 16; ++c) {  // scan all 2048 dst entries in chunks of 128
    if (t < 2) lcnt[t] = 0;
    __syncthreads();
    int ep = c * 128 + t;
    int d = edge_index[NE + ep];
    if (d == srcu) { int p = atomicAdd(&lcnt[0], 1); lst[0][p] = ep; }
    if (d == dstu) { int p = atomicAdd(&lcnt[1], 1); lst[1][p] = ep; }
    __syncthreads();
    int c0 = lcnt[0], c1 = lcnt[1];
    for (int i = 0; i < c0; ++i) acc_s += msg[lst[0][i] * 128 + t];
    for (int i = 0; i < c1; ++i) acc_d += msg[lst[1][i] * 128 + t];
    __syncthreads();
  }
  float hs = fmaxf(xsarr[e * 128 + t] + acc_s, 0.f);
  float hd = fmaxf(xdarr[e * 128 + t] + acc_d, 0.f);
  float xv = hs + hd;  // edge_h element t -> x[s][h]
  ((float*)xlds)[t] = xv;
  __syncthreads();

  // QKV
  float q = 0.f, kk = 0.f, vv = 0.f;
  for (int k4 = 0; k4 < 64; k4 += 4) {
    f32x4 xr = *(const f32x4*)&xlds[s][k4];
#pragma unroll
    for (int i = 0; i < 4; ++i) {
      int kidx = k4 + i;
      q  += xr[i] * Wq[kidx * 64 + h];
      kk += xr[i] * Wk[kidx * 64 + h];
      vv += xr[i] * Wv[kidx * 64 + h];
    }
  }
  klds[s][h] = kk;
  vlds[s][h] = vv;
  __syncthreads();
  // attention (S=2), wave s = row s
  float sc0 = wave_sum64(q * klds[0][h]) * 0.125f;
  float sc1 = wave_sum64(q * klds[1][h]) * 0.125f;
  float mx = fmaxf(sc0, sc1);
  float e0 = __expf(sc0 - mx), e1 = __expf(sc1 - mx);
  float pin = 1.f / (e0 + e1);
  float av = (e0 * pin) * vlds[0][h] + (e1 * pin) * vlds[1][h];
  alds[s][h] = av;
  __syncthreads();
  // output projection
  float o = 0.f;
  for (int k4 = 0; k4 < 64; k4 += 4) {
    f32x4 ar = *(const f32x4*)&alds[s][k4];
#pragma unroll
    for (int i = 0; i < 4; ++i) o += ar[i] * Wo[(k4 + i) * 64 + h];
  }
  float xa = xv + o;
  float mean = wave_sum64(xa) * (1.f / 64.f);
  float var = wave_sum64(xa * xa) * (1.f / 64.f) - mean * mean;
  float x1 = (xa - mean) * rsqrtf(var + 1e-5f);
  __syncthreads();
  ((float*)xlds)[t] = x1;
  __syncthreads();
  // FFN1: thread computes f = h*4..h*4+3
  f32x4 hh = {0.f, 0.f, 0.f, 0.f};
  int f0 = h * 4;
  for (int k4 = 0; k4 < 64; k4 += 4) {
    f32x4 xr = *(const f32x4*)&xlds[s][k4];
#pragma unroll
    for (int i = 0; i < 4; ++i) {
      f32x4 wrow = *(const f32x4*)&W1[(k4 + i) * 256 + f0];
#pragma unroll
      for (int jj = 0; jj < 4; ++jj) hh[jj] += xr[i] * wrow[jj];
    }
  }
#pragma unroll
  for (int jj = 0; jj < 4; ++jj) hh[jj] = fmaxf(hh[jj], 0.f);
  *(f32x4*)&h1[s][f0] = hh;
  __syncthreads();
  // FFN2
  float o2 = 0.f;
  for (int f4 = 0; f4 < 256; f4 += 4) {
    f32x4 hr = *(const f32x4*)&h1[s][f4];
#pragma unroll
    for (int i = 0; i < 4; ++i) o2 += hr[i] * W2[(f4 + i) * 64 + h];
  }
  float xb2 = x1 + o2;
  float mean2 = wave_sum64(xb2) * (1.f / 64.f);
  float var2 = wave_sum64(xb2 * xb2) * (1.f / 64.f) - mean2 * mean2;
  float x2 = (xb2 - mean2) * rsqrtf(var2 + 1e-5f);
  Xb[(e * 2 + s) * 64 + h] = f2bf(x2);
}

// ---------------- D1: sum of exp(logits) per row (MFMA) ---------------------
// Tile-resident: grid = 125 vocab tiles x 16 rowsplits. lm_Wt fragments for
// the block's tile are loaded ONCE into registers (32 VGPR) and reused across
// 4 rowgroups -> lm_Wt logical reads drop 64x (no L2-retention assumption).
__global__ __launch_bounds__(256) void d1_sums(
    const short* __restrict__ Xb, const short* __restrict__ lm_Wt,
    const float* __restrict__ lm_b, float* __restrict__ rsums) {
  int t = threadIdx.x;
  int w = t >> 6, l = t & 63;
  int lm = l & 15, lq = l >> 4;
  int tile = blockIdx.x >> 4;   // 0..124 (125*256 = 32000 exact)
  int rs = blockIdx.x & 15;     // 0..15
  int n0 = tile * 256 + w * 64;
  short8 bf[4][2];
#pragma unroll
  for (int nf = 0; nf < 4; ++nf)
#pragma unroll
    for (int ks = 0; ks < 2; ++ks)
      bf[nf][ks] = *(const short8*)(lm_Wt + (n0 + nf * 16 + lm) * 64 + ks * 32 + lq * 8);
  float bv[4];
#pragma unroll
  for (int nf = 0; nf < 4; ++nf) bv[nf] = lm_b[n0 + nf * 16 + lm];
  __shared__ float ls[4][64];
  for (int rg = 0; rg < 4; ++rg) {
    int mb0 = rs * 256 + rg * 64;
    short8 af[4][2];
#pragma unroll
    for (int mf = 0; mf < 4; ++mf)
#pragma unroll
      for (int ks = 0; ks < 2; ++ks)
        af[mf][ks] = *(const short8*)(Xb + (mb0 + mf * 16 + lm) * 64 + ks * 32 + lq * 8);
    f32x4 acc[4][4] = {};
#pragma unroll
    for (int ks = 0; ks < 2; ++ks)
#pragma unroll
      for (int mf = 0; mf < 4; ++mf)
#pragma unroll
        for (int nf = 0; nf < 4; ++nf)
          acc[mf][nf] = __builtin_amdgcn_mfma_f32_16x16x32_bf16(af[mf][ks], bf[nf][ks], acc[mf][nf], 0, 0, 0);
#pragma unroll
    for (int mf = 0; mf < 4; ++mf)
#pragma unroll
      for (int r = 0; r < 4; ++r) {
        float s = 0.f;
#pragma unroll
        for (int nf = 0; nf < 4; ++nf) s += __expf(acc[mf][nf][r] + bv[nf]);
        // reduce over the 16 lm lanes (vocab cols within the wave)
        s += __shfl_xor(s, 1, 64);
        s += __shfl_xor(s, 2, 64);
        s += __shfl_xor(s, 4, 64);
        s += __shfl_xor(s, 8, 64);
        if (lm == 0) ls[w][mf * 16 + lq * 4 + r] = s;
      }
    __syncthreads();
    if (t < 64) atomicAdd(&rsums[mb0 + t], ls[0][t] + ls[1][t] + ls[2][t] + ls[3][t]);
    __syncthreads();  // protect ls before next rowgroup overwrites it
  }
}

// ---------------- D2: recompute logits, write probs -------------------------
// Tile-resident like d1; swapped operands (A = lm_Wt -> lane holds 4
// consecutive vocab entries) for dwordx4 stores. Plain (L2-allocating)
// stores: nt variant measured +40..60us slower (round 5 vs baseline) --
// L2 write-combining of the 64B segments beats the bypass path.
__global__ __launch_bounds__(256) void d2_probs(
    const short* __restrict__ Xb, const short* __restrict__ lm_Wt,
    const float* __restrict__ lm_b, const float* __restrict__ rsums,
    float* __restrict__ out_probs) {
  int t = threadIdx.x;
  int w = t >> 6, l = t & 63;
  int lm = l & 15, lq = l >> 4;
  int tile = blockIdx.x >> 4;   // 0..124
  int rs = blockIdx.x & 15;     // 0..15
  int n0 = tile * 256 + w * 64;
  short8 wf[4][2];
#pragma unroll
  for (int nf = 0; nf < 4; ++nf)
#pragma unroll
    for (int ks = 0; ks < 2; ++ks)
      wf[nf][ks] = *(const short8*)(lm_Wt + (n0 + nf * 16 + lm) * 64 + ks * 32 + lq * 8);
  f32x4 bq[4];
#pragma unroll
  for (int nf = 0; nf < 4; ++nf)
    bq[nf] = *(const f32x4*)(lm_b + n0 + nf * 16 + lq * 4);
  for (int rg = 0; rg < 4; ++rg) {
    int mb0 = rs * 256 + rg * 64;
    short8 xf[4][2];
#pragma unroll
    for (int mf = 0; mf < 4; ++mf)
#pragma unroll
      for (int ks = 0; ks < 2; ++ks)
        xf[mf][ks] = *(const short8*)(Xb + (mb0 + mf * 16 + lm) * 64 + ks * 32 + lq * 8);
    float iv[4];
#pragma unroll
    for (int mf = 0; mf < 4; ++mf) iv[mf] = 1.f / rsums[mb0 + mf * 16 + lm];
    f32x4 acc[4][4] = {};
#pragma unroll
    for (int ks = 0; ks < 2; ++ks)
#pragma unroll
      for (int mf = 0; mf < 4; ++mf)
#pragma unroll
        for (int nf = 0; nf < 4; ++nf)
          acc[mf][nf] = __builtin_amdgcn_mfma_f32_16x16x32_bf16(wf[nf][ks], xf[mf][ks], acc[mf][nf], 0, 0, 0);
#pragma unroll
    for (int mf = 0; mf < 4; ++mf) {
      size_t rowbase = (size_t)(mb0 + mf * 16 + lm) * VOC;
#pragma unroll
      for (int nf = 0; nf < 4; ++nf) {
        f32x4 p;
#pragma unroll
        for (int r = 0; r < 4; ++r)
          p[r] = __expf(acc[mf][nf][r] + bq[nf][r]) * iv[mf];
        *(f32x4*)(out_probs + rowbase + n0 + nf * 16 + lq * 4) = p;
      }
    }
  }
}

extern "C" void kernel_launch(void* const* d_in, const int* in_sizes, int n_in,
                              void* d_out, int out_size, void* d_ws, size_t ws_size,
                              hipStream_t stream) {
  const int* node_tokens = (const int*)d_in[0];
  const int* edge_tokens = (const int*)d_in[1];
  const int* edge_index  = (const int*)d_in[2];
  const float* embed     = (const float*)d_in[3];
  const float* W_self    = (const float*)d_in[4];
  const float* W_nbr     = (const float*)d_in[5];
  const float* Wq        = (const float*)d_in[6];
  const float* Wk        = (const float*)d_in[7];
  const float* Wv        = (const float*)d_in[8];
  const float* Wo        = (const float*)d_in[9];
  const float* W1        = (const float*)d_in[10];
  const float* W2        = (const float*)d_in[11];
  const float* lm_W      = (const float*)d_in[12];
  const float* lm_b      = (const float*)d_in[13];

  char* ws = (char*)d_ws;
  short* lm_Wt  = (short*)(ws + OFF_LMWT);
  short* Wnbrt  = (short*)(ws + OFF_WNBRT);
  short* Wselft = (short*)(ws + OFF_WSELFT);
  short* A_all  = (short*)(ws + OFF_AALL);
  float* msg    = (float*)(ws + OFF_MSG);
  float* xsarr  = (float*)(ws + OFF_XS);
  float* xdarr  = (float*)(ws + OFF_XD);
  short* Xb     = (short*)(ws + OFF_XB);
  float* rsums  = (float*)(ws + OFF_RSUMS);
  float* out    = (float*)d_out;  // [16384 labels][131072000 probs]

  k0_prep<<<549, 256, 0, stream>>>(lm_W, W_nbr, W_self, edge_tokens,
                                   lm_Wt, Wnbrt, Wselft, rsums, out);
  k1a_gather<<<1536, 256, 0, stream>>>(node_tokens, edge_tokens, edge_index,
                                       embed, A_all);
  k1b_gemm<<<192, 256, 0, stream>>>(A_all, Wnbrt, Wselft, msg, xsarr, xdarr);
  k23_fused<<<2048, 128, 0, stream>>>(edge_index, msg, xsarr, xdarr,
                                      Wq, Wk, Wv, Wo, W1, W2, Xb);
  d1_sums<<<2000, 256, 0, stream>>>(Xb, lm_Wt, lm_b, rsums);
  d2_probs<<<2000, 256, 0, stream>>>(Xb, lm_Wt, lm_b, rsums, out + 16384);
}